// Round 8
// baseline (254.249 us; speedup 1.0000x reference)
//
#include <hip/hip_runtime.h>
#include <hip/hip_bf16.h>
#include <cstdint>
#include <cstddef>

constexpr int Bn = 8;
constexpr int Nn = 2048;
constexpr int Dn = 128;

typedef __bf16 bf16x8 __attribute__((ext_vector_type(8)));
typedef float f32x4 __attribute__((ext_vector_type(4)));

// -----------------------------------------------------------------------------
// Kernel 1 (unchanged): h = x@W (fp32), s1 = h@a1, s2 = h@a2, hT bf16 [B][D][N].
// -----------------------------------------------------------------------------
__global__ __launch_bounds__(256) void gat_k1(
    const float* __restrict__ x, const float* __restrict__ W,
    const float* __restrict__ a_vec,
    __bf16* __restrict__ hT, float* __restrict__ s1, float* __restrict__ s2) {
  __shared__ __align__(16) float Wl[64 * 144];  // [k][c-swizzled], 36.9KB
  __shared__ __align__(16) float xL[32 * 132];  // [r][k], 16.9KB

  const int t = threadIdx.x;
  const int r0 = blockIdx.x * 32;
  const int b = r0 >> 11;
  const int n0 = r0 & (Nn - 1);
  const int rp = (t >> 4) << 1;                 // row pair base 0..30
  const int c0 = (t & 15) << 3;                 // 0..120
  const int c0p = c0 + ((c0 >> 5) << 2);        // pad 4 dwords every 32

  float acc[2][8];
#pragma unroll
  for (int r = 0; r < 2; ++r)
#pragma unroll
    for (int c = 0; c < 8; ++c) acc[r][c] = 0.f;

  // stage xL: 32x128 fp32
#pragma unroll
  for (int it = 0; it < 4; ++it) {
    int idx = t + (it << 8);
    int rr = idx >> 5, kc = (idx & 31) << 2;
    *(float4*)(xL + rr * 132 + kc) = *(const float4*)(x + (size_t)(r0 + rr) * Dn + kc);
  }

  for (int ph = 0; ph < 2; ++ph) {
    if (ph) __syncthreads();  // phase-0 readers done before restage
#pragma unroll
    for (int it = 0; it < 8; ++it) {
      int idx = t + (it << 8);
      int kk = idx >> 5, c4 = (idx & 31) << 2;
      int dsto = kk * 144 + c4 + ((c4 >> 5) << 2);
      *(float4*)(Wl + dsto) = *(const float4*)(W + (size_t)((ph << 6) + kk) * Dn + c4);
    }
    __syncthreads();
    const float* xrow = xL + rp * 132 + (ph << 6);
    for (int k = 0; k < 64; ++k) {
      float xa0 = xrow[k];
      float xa1 = xrow[132 + k];
      float4 w0 = *(const float4*)(Wl + k * 144 + c0p);
      float4 w1 = *(const float4*)(Wl + k * 144 + c0p + 4);
      float ws[8] = {w0.x, w0.y, w0.z, w0.w, w1.x, w1.y, w1.z, w1.w};
#pragma unroll
      for (int c = 0; c < 8; ++c) {
        acc[0][c] = fmaf(xa0, ws[c], acc[0][c]);
        acc[1][c] = fmaf(xa1, ws[c], acc[1][c]);
      }
    }
  }

  // s1/s2: partial dots over my 8 cols, reduce across 16 col-groups (lanes&15)
  float q1[2] = {0.f, 0.f}, q2[2] = {0.f, 0.f};
#pragma unroll
  for (int c = 0; c < 8; ++c) {
    float a1c = a_vec[c0 + c];
    float a2c = a_vec[Dn + c0 + c];
    q1[0] = fmaf(acc[0][c], a1c, q1[0]);
    q1[1] = fmaf(acc[1][c], a1c, q1[1]);
    q2[0] = fmaf(acc[0][c], a2c, q2[0]);
    q2[1] = fmaf(acc[1][c], a2c, q2[1]);
  }
#pragma unroll
  for (int d = 1; d < 16; d <<= 1) {
    q1[0] += __shfl_xor(q1[0], d);
    q1[1] += __shfl_xor(q1[1], d);
    q2[0] += __shfl_xor(q2[0], d);
    q2[1] += __shfl_xor(q2[1], d);
  }
  if ((t & 15) == 0) {
    s1[b * Nn + n0 + rp] = q1[0];
    s1[b * Nn + n0 + rp + 1] = q1[1];
    s2[b * Nn + n0 + rp] = q2[0];
    s2[b * Nn + n0 + rp + 1] = q2[1];
  }

  // hT store: rows rp/rp+1 are adjacent n -> pack 2 bf16 per u32
#pragma unroll
  for (int c = 0; c < 8; ++c) {
    union { __bf16 h[2]; uint32_t u; } pk;
    pk.h[0] = (__bf16)acc[0][c];
    pk.h[1] = (__bf16)acc[1][c];
    *(uint32_t*)(hT + (size_t)(b * Dn + c0 + c) * Nn + n0 + rp) = pk.u;
  }
}

// -----------------------------------------------------------------------------
// kpack: adj -> per-(row,lane) u32 masks in k3's nibble layout.
// bit (k*4+e) = adj[row][k*256 + lane*4 + e] > 0.  512 blocks x 256 (4 rows/blk).
// -----------------------------------------------------------------------------
__global__ __launch_bounds__(256) void gat_kpack(
    const int* __restrict__ adj, uint32_t* __restrict__ pkm) {
  const int t = threadIdx.x;
  const int row = (blockIdx.x << 2) + (t >> 6);
  const int l = t & 63;
  const int* __restrict__ ar = adj + (size_t)row * Nn + (l << 2);
  uint32_t m = 0;
#pragma unroll
  for (int k = 0; k < 8; ++k) {
    int4 a = *(const int4*)(ar + (k << 8));
    uint32_t nib = (a.x > 0 ? 1u : 0u) | (a.y > 0 ? 2u : 0u) |
                   (a.z > 0 ? 4u : 0u) | (a.w > 0 ? 8u : 0u);
    m |= nib << (k << 2);
  }
  pkm[(row << 6) + l] = m;
}

// -----------------------------------------------------------------------------
// Kernel 2 (out only): R7 structure minus ALL alpha stores. Phase A captures
// adj masks into 4 VGPR words; phase B = pure {sj LDS + exp + hT L2 load +
// MFMA} (no global stores in the loop -> no vmcnt store-drain coupling).
// Writes out (8 MB) + invl[b][i] (for k3). 1024 blocks x 256 thr.
// -----------------------------------------------------------------------------
__global__ __launch_bounds__(256, 4) void gat_k2(
    const int* __restrict__ adj, const __bf16* __restrict__ hT,
    const float* __restrict__ s1, const float* __restrict__ s2,
    float* __restrict__ out, float* __restrict__ invl_out) {
  __shared__ __align__(16) float accL[4 * 16 * 128];  // 32KB; first 8KB = sj
  __shared__ float lq[4][16];
  float* const sj = accL;  // alias: sj dead before accL written (barriered)

  const int t = threadIdx.x;
  const int b = blockIdx.x >> 7;
  const int i0 = (blockIdx.x & 127) << 4;
  const int jq = t >> 6, lane = t & 63;
  const int q16 = lane >> 4, m16 = lane & 15;
  const int jo = (jq << 9) + (q16 << 3);

  *(float4*)(sj + (t << 3)) = *(const float4*)(s2 + b * Nn + (t << 3));
  *(float4*)(sj + (t << 3) + 4) = *(const float4*)(s2 + b * Nn + (t << 3) + 4);
  asm volatile("s_waitcnt lgkmcnt(0)\n\ts_barrier" ::: "memory");

  const int i = i0 + m16;
  const float si = s1[b * Nn + i];
  const int* __restrict__ adjrow = adj + (size_t)i * Nn + jo;
  const float* __restrict__ sjl = sj + jo;

  // Phase A: partial denominator + mask capture (window JT -> byte (JT&3) of
  // word JT>>2; bit e within byte).
  float l = 0.f;
  uint32_t mb0 = 0, mb1 = 0, mb2 = 0, mb3 = 0;
#define PHA(JT, MW)                                                           \
  {                                                                           \
    int o = (JT) << 5;                                                        \
    int4 am0 = *(const int4*)(adjrow + o);                                    \
    int4 am1 = *(const int4*)(adjrow + o + 4);                                \
    float4 v0 = *(const float4*)(sjl + o);                                    \
    float4 v1 = *(const float4*)(sjl + o + 4);                                \
    float e0 = si + v0.x; e0 = fmaxf(e0, 0.2f * e0);                          \
    float e1 = si + v0.y; e1 = fmaxf(e1, 0.2f * e1);                          \
    float e2 = si + v0.z; e2 = fmaxf(e2, 0.2f * e2);                          \
    float e3 = si + v0.w; e3 = fmaxf(e3, 0.2f * e3);                          \
    float e4 = si + v1.x; e4 = fmaxf(e4, 0.2f * e4);                          \
    float e5 = si + v1.y; e5 = fmaxf(e5, 0.2f * e5);                          \
    float e6 = si + v1.z; e6 = fmaxf(e6, 0.2f * e6);                          \
    float e7 = si + v1.w; e7 = fmaxf(e7, 0.2f * e7);                          \
    l += (am0.x > 0) ? __expf(e0) : 0.f;                                      \
    l += (am0.y > 0) ? __expf(e1) : 0.f;                                      \
    l += (am0.z > 0) ? __expf(e2) : 0.f;                                      \
    l += (am0.w > 0) ? __expf(e3) : 0.f;                                      \
    l += (am1.x > 0) ? __expf(e4) : 0.f;                                      \
    l += (am1.y > 0) ? __expf(e5) : 0.f;                                      \
    l += (am1.z > 0) ? __expf(e6) : 0.f;                                      \
    l += (am1.w > 0) ? __expf(e7) : 0.f;                                      \
    uint32_t bits = (am0.x > 0 ? 1u : 0u) | (am0.y > 0 ? 2u : 0u) |           \
                    (am0.z > 0 ? 4u : 0u) | (am0.w > 0 ? 8u : 0u) |           \
                    (am1.x > 0 ? 16u : 0u) | (am1.y > 0 ? 32u : 0u) |         \
                    (am1.z > 0 ? 64u : 0u) | (am1.w > 0 ? 128u : 0u);         \
    MW |= bits << (((JT) & 3) << 3);                                          \
  }
  PHA(0, mb0) PHA(1, mb0) PHA(2, mb0) PHA(3, mb0)
  PHA(4, mb1) PHA(5, mb1) PHA(6, mb1) PHA(7, mb1)
  PHA(8, mb2) PHA(9, mb2) PHA(10, mb2) PHA(11, mb2)
  PHA(12, mb3) PHA(13, mb3) PHA(14, mb3) PHA(15, mb3)
#undef PHA

  l += __shfl_xor(l, 16);
  l += __shfl_xor(l, 32);
  if (q16 == 0) lq[jq][m16] = l;
  asm volatile("s_waitcnt lgkmcnt(0)\n\ts_barrier" ::: "memory");
  const float il = 1.f / (lq[0][m16] + lq[1][m16] + lq[2][m16] + lq[3][m16]);
  if (t < 16) invl_out[b * Nn + i0 + t] = il;  // t<16: jq=0,q16=0,m16=t

  // Phase B: 16 windows, loads+MFMA only (no global stores).
  f32x4 acc0 = {0.f, 0.f, 0.f, 0.f}, acc1 = {0.f, 0.f, 0.f, 0.f};
  f32x4 acc2 = {0.f, 0.f, 0.f, 0.f}, acc3 = {0.f, 0.f, 0.f, 0.f};
  f32x4 acc4 = {0.f, 0.f, 0.f, 0.f}, acc5 = {0.f, 0.f, 0.f, 0.f};
  f32x4 acc6 = {0.f, 0.f, 0.f, 0.f}, acc7 = {0.f, 0.f, 0.f, 0.f};
  const __bf16* __restrict__ hrow =
      hT + (size_t)b * Dn * Nn + (size_t)m16 * Nn + jo;

#define MF(DT, A)                                                             \
  {                                                                           \
    bf16x8 bv = *(const bf16x8*)(hp + (size_t)(DT) * (16 * Nn));              \
    A = __builtin_amdgcn_mfma_f32_16x16x32_bf16(af, bv, A, 0, 0, 0);          \
  }
#define PHB(JT, MW)                                                           \
  {                                                                           \
    const int sh = ((JT) & 3) << 3;                                           \
    int o = (JT) << 5;                                                        \
    float4 v0 = *(const float4*)(sjl + o);                                    \
    float4 v1 = *(const float4*)(sjl + o + 4);                                \
    float e0 = si + v0.x; e0 = fmaxf(e0, 0.2f * e0);                          \
    float e1 = si + v0.y; e1 = fmaxf(e1, 0.2f * e1);                          \
    float e2 = si + v0.z; e2 = fmaxf(e2, 0.2f * e2);                          \
    float e3 = si + v0.w; e3 = fmaxf(e3, 0.2f * e3);                          \
    float e4 = si + v1.x; e4 = fmaxf(e4, 0.2f * e4);                          \
    float e5 = si + v1.y; e5 = fmaxf(e5, 0.2f * e5);                          \
    float e6 = si + v1.z; e6 = fmaxf(e6, 0.2f * e6);                          \
    float e7 = si + v1.w; e7 = fmaxf(e7, 0.2f * e7);                          \
    float a0 = ((MW >> (sh + 0)) & 1u) ? __expf(e0) * il : 0.f;               \
    float a1 = ((MW >> (sh + 1)) & 1u) ? __expf(e1) * il : 0.f;               \
    float a2 = ((MW >> (sh + 2)) & 1u) ? __expf(e2) * il : 0.f;               \
    float a3 = ((MW >> (sh + 3)) & 1u) ? __expf(e3) * il : 0.f;               \
    float a4 = ((MW >> (sh + 4)) & 1u) ? __expf(e4) * il : 0.f;               \
    float a5 = ((MW >> (sh + 5)) & 1u) ? __expf(e5) * il : 0.f;               \
    float a6 = ((MW >> (sh + 6)) & 1u) ? __expf(e6) * il : 0.f;               \
    float a7 = ((MW >> (sh + 7)) & 1u) ? __expf(e7) * il : 0.f;               \
    bf16x8 af;                                                                \
    af[0] = (__bf16)a0; af[1] = (__bf16)a1;                                   \
    af[2] = (__bf16)a2; af[3] = (__bf16)a3;                                   \
    af[4] = (__bf16)a4; af[5] = (__bf16)a5;                                   \
    af[6] = (__bf16)a6; af[7] = (__bf16)a7;                                   \
    const __bf16* hp = hrow + o;                                              \
    MF(0, acc0) MF(1, acc1) MF(2, acc2) MF(3, acc3)                           \
    MF(4, acc4) MF(5, acc5) MF(6, acc6) MF(7, acc7)                           \
  }
  PHB(0, mb0) PHB(1, mb0) PHB(2, mb0) PHB(3, mb0)
  PHB(4, mb1) PHB(5, mb1) PHB(6, mb1) PHB(7, mb1)
  PHB(8, mb2) PHB(9, mb2) PHB(10, mb2) PHB(11, mb2)
  PHB(12, mb3) PHB(13, mb3) PHB(14, mb3) PHB(15, mb3)
#undef PHB
#undef MF

  // Phase C: 4-way cross-wave acc reduce via accL (aliases sj).
  asm volatile("s_waitcnt lgkmcnt(0)\n\ts_barrier" ::: "memory");
#define WR(DT, A)                                                             \
  {                                                                           \
    _Pragma("unroll")                                                         \
    for (int r = 0; r < 4; ++r)                                               \
      accL[(jq << 11) + (((q16 << 2) + r) << 7) + ((DT) << 4) + m16] = A[r];  \
  }
  WR(0, acc0) WR(1, acc1) WR(2, acc2) WR(3, acc3)
  WR(4, acc4) WR(5, acc5) WR(6, acc6) WR(7, acc7)
#undef WR
  asm volatile("s_waitcnt lgkmcnt(0)\n\ts_barrier" ::: "memory");
  {
    const int row = t >> 4, dc = (t & 15) << 3;
    const float* p = accL + (row << 7) + dc;
    f32x4 u0 = *(const f32x4*)(p);
    f32x4 u1 = *(const f32x4*)(p + 4);
#pragma unroll
    for (int q = 1; q < 4; ++q) {
      u0 += *(const f32x4*)(p + (q << 11));
      u1 += *(const f32x4*)(p + (q << 11) + 4);
    }
    float* op = out + ((size_t)(b * Nn + i0 + row) << 7) + dc;
    __builtin_nontemporal_store(u0, (f32x4*)op);
    __builtin_nontemporal_store(u1, (f32x4*)(op + 4));
  }
}

// -----------------------------------------------------------------------------
// Kernel 3 (alpha, fill-shaped): 1024 blocks x 256 thr; 16 rows/block,
// 4 rows/wave. Per row-group: hoist 4 mask u32 + 4 si + 4 il, then 32 pure
// NT store instructions, each 1KB-contiguous (64 lanes x 16B). One load-drain
// per 32KB stored. Alpha bitwise-identical (same exp inputs, same il).
// -----------------------------------------------------------------------------
__global__ __launch_bounds__(256) void gat_k3(
    const uint32_t* __restrict__ pkm, const float* __restrict__ s1,
    const float* __restrict__ invl, const float* __restrict__ s2,
    float* __restrict__ alpha) {
  __shared__ __align__(16) float sj[Nn];  // 8 KB

  const int t = threadIdx.x;
  const int b = blockIdx.x >> 7;
  const int i0 = (blockIdx.x & 127) << 4;
  const int w = t >> 6, l = t & 63;

  *(float4*)(sj + (t << 3)) = *(const float4*)(s2 + b * Nn + (t << 3));
  *(float4*)(sj + (t << 3) + 4) = *(const float4*)(s2 + b * Nn + (t << 3) + 4);
  __syncthreads();

  const int ib = i0 + (w << 2);
  // hoisted gather: 4 masks + 4 si + 4 il (then pure stores)
  uint32_t m0 = pkm[((ib + 0) << 6) + l];
  uint32_t m1 = pkm[((ib + 1) << 6) + l];
  uint32_t m2 = pkm[((ib + 2) << 6) + l];
  uint32_t m3 = pkm[((ib + 3) << 6) + l];
  float si0 = s1[b * Nn + ib + 0], il0 = invl[b * Nn + ib + 0];
  float si1 = s1[b * Nn + ib + 1], il1 = invl[b * Nn + ib + 1];
  float si2 = s1[b * Nn + ib + 2], il2 = invl[b * Nn + ib + 2];
  float si3 = s1[b * Nn + ib + 3], il3 = invl[b * Nn + ib + 3];

#define ROW(RR, M, SI, IL)                                                    \
  {                                                                           \
    float* __restrict__ arow =                                                \
        alpha + ((size_t)(b * Nn + ib + (RR)) << 11) + (l << 2);              \
    _Pragma("unroll")                                                         \
    for (int k = 0; k < 8; ++k) {                                             \
      float4 sv = *(const float4*)(sj + (k << 8) + (l << 2));                 \
      float e0 = (SI) + sv.x; e0 = fmaxf(e0, 0.2f * e0);                      \
      float e1 = (SI) + sv.y; e1 = fmaxf(e1, 0.2f * e1);                      \
      float e2 = (SI) + sv.z; e2 = fmaxf(e2, 0.2f * e2);                      \
      float e3 = (SI) + sv.w; e3 = fmaxf(e3, 0.2f * e3);                      \
      float a0 = (((M) >> ((k << 2) + 0)) & 1u) ? __expf(e0) * (IL) : 0.f;    \
      float a1 = (((M) >> ((k << 2) + 1)) & 1u) ? __expf(e1) * (IL) : 0.f;    \
      float a2 = (((M) >> ((k << 2) + 2)) & 1u) ? __expf(e2) * (IL) : 0.f;    \
      float a3 = (((M) >> ((k << 2) + 3)) & 1u) ? __expf(e3) * (IL) : 0.f;    \
      f32x4 av = {a0, a1, a2, a3};                                            \
      __builtin_nontemporal_store(av, (f32x4*)(arow + (k << 8)));             \
    }                                                                         \
  }
  ROW(0, m0, si0, il0)
  ROW(1, m1, si1, il1)
  ROW(2, m2, si2, il2)
  ROW(3, m3, si3, il3)
#undef ROW
}

extern "C" void kernel_launch(void* const* d_in, const int* in_sizes, int n_in,
                              void* d_out, int out_size, void* d_ws, size_t ws_size,
                              hipStream_t stream) {
  const float* x = (const float*)d_in[0];
  const int* adj = (const int*)d_in[1];
  const float* W = (const float*)d_in[2];
  const float* a_vec = (const float*)d_in[3];

  float* out = (float*)d_out;
  float* alpha = out + (size_t)Bn * Nn * Dn;  // outputs concatenated: (out, alpha)

  char* ws = (char*)d_ws;
  __bf16* hT = (__bf16*)ws;                               // 4 MiB
  float* s1 = (float*)(ws + (size_t)Bn * Dn * Nn * 2);    // B*N fp32
  float* s2 = s1 + (size_t)Bn * Nn;
  float* invl = s2 + (size_t)Bn * Nn;                     // B*N fp32
  uint32_t* pkm = (uint32_t*)(invl + (size_t)Bn * Nn);    // N*64 u32 = 512 KB

  gat_k1<<<512, 256, 0, stream>>>(x, W, a_vec, hT, s1, s2);
  gat_kpack<<<512, 256, 0, stream>>>(adj, pkm);
  gat_k2<<<1024, 256, 0, stream>>>(adj, hT, s1, s2, out, invl);
  gat_k3<<<1024, 256, 0, stream>>>(pkm, s1, invl, s2, alpha);
}

// Round 10
// 193.066 us; speedup vs baseline: 1.3169x; 1.3169x over previous
//
#include <hip/hip_runtime.h>
#include <hip/hip_bf16.h>
#include <cstdint>
#include <cstddef>

constexpr int Bn = 8;
constexpr int Nn = 2048;
constexpr int Dn = 128;

typedef __bf16 bf16x8 __attribute__((ext_vector_type(8)));
typedef float f32x4 __attribute__((ext_vector_type(4)));

#define AS1 __attribute__((address_space(1)))
#define AS3 __attribute__((address_space(3)))

// async global->LDS, 16B per lane; LDS dest must be wave-uniform base (+lane*16)
static __device__ __forceinline__ void gl_lds16(const void* g, void* l) {
  __builtin_amdgcn_global_load_lds((AS1 const void*)g, (AS3 void*)l, 16, 0, 0);
}

// -----------------------------------------------------------------------------
// Kernel 1 (unchanged): h = x@W (fp32), s1 = h@a1, s2 = h@a2, hT bf16 [B][D][N].
// -----------------------------------------------------------------------------
__global__ __launch_bounds__(256) void gat_k1(
    const float* __restrict__ x, const float* __restrict__ W,
    const float* __restrict__ a_vec,
    __bf16* __restrict__ hT, float* __restrict__ s1, float* __restrict__ s2) {
  __shared__ __align__(16) float Wl[64 * 144];  // [k][c-swizzled], 36.9KB
  __shared__ __align__(16) float xL[32 * 132];  // [r][k], 16.9KB

  const int t = threadIdx.x;
  const int r0 = blockIdx.x * 32;
  const int b = r0 >> 11;
  const int n0 = r0 & (Nn - 1);
  const int rp = (t >> 4) << 1;                 // row pair base 0..30
  const int c0 = (t & 15) << 3;                 // 0..120
  const int c0p = c0 + ((c0 >> 5) << 2);        // pad 4 dwords every 32

  float acc[2][8];
#pragma unroll
  for (int r = 0; r < 2; ++r)
#pragma unroll
    for (int c = 0; c < 8; ++c) acc[r][c] = 0.f;

  // stage xL: 32x128 fp32
#pragma unroll
  for (int it = 0; it < 4; ++it) {
    int idx = t + (it << 8);
    int rr = idx >> 5, kc = (idx & 31) << 2;
    *(float4*)(xL + rr * 132 + kc) = *(const float4*)(x + (size_t)(r0 + rr) * Dn + kc);
  }

  for (int ph = 0; ph < 2; ++ph) {
    if (ph) __syncthreads();  // phase-0 readers done before restage
#pragma unroll
    for (int it = 0; it < 8; ++it) {
      int idx = t + (it << 8);
      int kk = idx >> 5, c4 = (idx & 31) << 2;
      int dsto = kk * 144 + c4 + ((c4 >> 5) << 2);
      *(float4*)(Wl + dsto) = *(const float4*)(W + (size_t)((ph << 6) + kk) * Dn + c4);
    }
    __syncthreads();
    const float* xrow = xL + rp * 132 + (ph << 6);
    for (int k = 0; k < 64; ++k) {
      float xa0 = xrow[k];
      float xa1 = xrow[132 + k];
      float4 w0 = *(const float4*)(Wl + k * 144 + c0p);
      float4 w1 = *(const float4*)(Wl + k * 144 + c0p + 4);
      float ws[8] = {w0.x, w0.y, w0.z, w0.w, w1.x, w1.y, w1.z, w1.w};
#pragma unroll
      for (int c = 0; c < 8; ++c) {
        acc[0][c] = fmaf(xa0, ws[c], acc[0][c]);
        acc[1][c] = fmaf(xa1, ws[c], acc[1][c]);
      }
    }
  }

  // s1/s2: partial dots over my 8 cols, reduce across 16 col-groups (lanes&15)
  float q1[2] = {0.f, 0.f}, q2[2] = {0.f, 0.f};
#pragma unroll
  for (int c = 0; c < 8; ++c) {
    float a1c = a_vec[c0 + c];
    float a2c = a_vec[Dn + c0 + c];
    q1[0] = fmaf(acc[0][c], a1c, q1[0]);
    q1[1] = fmaf(acc[1][c], a1c, q1[1]);
    q2[0] = fmaf(acc[0][c], a2c, q2[0]);
    q2[1] = fmaf(acc[1][c], a2c, q2[1]);
  }
#pragma unroll
  for (int d = 1; d < 16; d <<= 1) {
    q1[0] += __shfl_xor(q1[0], d);
    q1[1] += __shfl_xor(q1[1], d);
    q2[0] += __shfl_xor(q2[0], d);
    q2[1] += __shfl_xor(q2[1], d);
  }
  if ((t & 15) == 0) {
    s1[b * Nn + n0 + rp] = q1[0];
    s1[b * Nn + n0 + rp + 1] = q1[1];
    s2[b * Nn + n0 + rp] = q2[0];
    s2[b * Nn + n0 + rp + 1] = q2[1];
  }

  // hT store: rows rp/rp+1 are adjacent n -> pack 2 bf16 per u32
#pragma unroll
  for (int c = 0; c < 8; ++c) {
    union { __bf16 h[2]; uint32_t u; } pk;
    pk.h[0] = (__bf16)acc[0][c];
    pk.h[1] = (__bf16)acc[1][c];
    *(uint32_t*)(hT + (size_t)(b * Dn + c0 + c) * Nn + n0 + rp) = pk.u;
  }
}

// -----------------------------------------------------------------------------
// kpack: adj -> per-(row,lane) u32 masks; bit (k*4+e) = adj[row][k*256+l*4+e]>0.
// Stream-once (16 MB read, 512 KB write). 512 blocks x 256 thr (4 rows/block).
// -----------------------------------------------------------------------------
__global__ __launch_bounds__(256) void gat_kpack(
    const int* __restrict__ adj, uint32_t* __restrict__ pkm) {
  const int t = threadIdx.x;
  const int row = (blockIdx.x << 2) + (t >> 6);
  const int l = t & 63;
  const int* __restrict__ ar = adj + (size_t)row * Nn + (l << 2);
  uint32_t m = 0;
#pragma unroll
  for (int k = 0; k < 8; ++k) {
    int4 a = *(const int4*)(ar + (k << 8));
    uint32_t nib = (a.x > 0 ? 1u : 0u) | (a.y > 0 ? 2u : 0u) |
                   (a.z > 0 ? 4u : 0u) | (a.w > 0 ? 8u : 0u);
    m |= nib << (k << 2);
  }
  pkm[(row << 6) + l] = m;
}

// -----------------------------------------------------------------------------
// Kernel 2 = R2's best (fused, hl dbuf via gl_lds, vmcnt(1) barrier, in-loop
// NT alpha stores, MFMA) with TWO residency edits:
//  (1) XCD-locality swizzle: b = bid&7, i0 = (bid>>3)*32 -> each XCD serves
//      exactly one batch; hT[b] (512KB) + pkm (512KB) L2-resident.
//  (2) adj replaced by pkm bitmasks (4 u32/thread) -> no 16MB adj stream
//      thrashing the 4MB per-XCD L2.
// Mask mapping (verified): j = cc*64+sub*4+e -> word pk[(cc&3)*16+sub],
// bit ((cc>>2)<<2)+e, cc = g*8+u.
// -----------------------------------------------------------------------------
__global__ __launch_bounds__(512) void gat_k2(
    const uint32_t* __restrict__ pkm, const __bf16* __restrict__ hT,
    const float* __restrict__ s1, const float* __restrict__ s2,
    float* __restrict__ out, float* __restrict__ alpha) {
  __shared__ __align__(16) float sj[Nn];            // 8 KB
  __shared__ float siv[32], invl[32];
  __shared__ __align__(16) __bf16 Pl[2][32 * 72];   // 9 KB, padded pitch
  __shared__ __align__(16) __bf16 hl[2][128 * 64];  // 32 KB, swizzled

  const int t = threadIdx.x;
  const int b = blockIdx.x & 7;                 // XCD-locality: batch = XCD
  const int i0 = (blockIdx.x >> 3) << 5;
  const int w = t >> 6, lane = t & 63;
  const int ii = t >> 4, sub = t & 15;
  const int lrow = lane >> 3, ccs = lane & 7;
  const __bf16* __restrict__ hTb = hT + (size_t)b * Dn * Nn;

  // prologue: prefetch j-tile 0 into hl[0] (drained at first __syncthreads)
#pragma unroll
  for (int inst = 0; inst < 2; ++inst) {
    int row = (w << 4) + (inst << 3) + lrow;
    gl_lds16(hTb + (size_t)row * Nn + ((ccs ^ lrow) << 3),
             &hl[0][((w << 4) + (inst << 3)) << 6]);
  }

  *(float4*)(sj + (t << 2)) = *(const float4*)(s2 + b * Nn + (t << 2));
  if (t < 32) siv[t] = s1[b * Nn + i0 + t];
  __syncthreads();  // full drain: tile0 resident, sj/siv visible

  const int i = i0 + ii;
  const float si = siv[ii];

  // masks: 4 u32 per thread cover all 128 j-slots of this thread
  const uint32_t* __restrict__ pk = pkm + ((size_t)i << 6);
  const uint32_t pk0 = pk[sub];
  const uint32_t pk1 = pk[sub + 16];
  const uint32_t pk2 = pk[sub + 32];
  const uint32_t pk3 = pk[sub + 48];

  // pass 1: l_i = sum_j mask * exp(lrelu(si+sj)) — no adj reads
  float l = 0.f;
  for (int g = 0; g < 4; ++g) {
    const int shg = g << 3;
#pragma unroll
    for (int u = 0; u < 8; ++u) {
      int j = (((g << 3) + u) << 6) + (sub << 2);
      float4 sv = *(const float4*)(sj + j);
      uint32_t mw = (u & 2) ? ((u & 1) ? pk3 : pk2) : ((u & 1) ? pk1 : pk0);
      int sh = shg + ((u >> 2) << 2);
      float e0 = si + sv.x; e0 = fmaxf(e0, 0.2f * e0);
      float e1 = si + sv.y; e1 = fmaxf(e1, 0.2f * e1);
      float e2 = si + sv.z; e2 = fmaxf(e2, 0.2f * e2);
      float e3 = si + sv.w; e3 = fmaxf(e3, 0.2f * e3);
      l += ((mw >> (sh + 0)) & 1u) ? __expf(e0) : 0.f;
      l += ((mw >> (sh + 1)) & 1u) ? __expf(e1) : 0.f;
      l += ((mw >> (sh + 2)) & 1u) ? __expf(e2) : 0.f;
      l += ((mw >> (sh + 3)) & 1u) ? __expf(e3) : 0.f;
    }
  }

  l += __shfl_xor(l, 1);
  l += __shfl_xor(l, 2);
  l += __shfl_xor(l, 4);
  l += __shfl_xor(l, 8);
  if (sub == 0) invl[ii] = 1.f / l;
  __syncthreads();  // full drain (vmcnt=0): VM queue empty entering pipeline
  const float il = invl[ii];

  const int iw = (w & 1) << 4;
  const int nd0 = (w >> 1) << 5;
  const int q16 = lane >> 4, m16 = lane & 15;
  f32x4 acc0 = {0.f, 0.f, 0.f, 0.f}, acc1 = {0.f, 0.f, 0.f, 0.f};
  float* __restrict__ arow = alpha + ((size_t)(b * Nn + i) << 11);

  for (int g = 0; g < 4; ++g) {
    const int shg = g << 3;
#pragma unroll
    for (int u = 0; u < 8; ++u) {
      const int buf = u & 1;                     // static per inner iteration
      const int j0r = (g << 9) + (u << 6);       // jt*64
      // alpha for my 4 j's (mask from register bits): fp32 NT -> global,
      // bf16 -> Pl[buf]
      {
        int j = j0r + (sub << 2);
        float4 sv = *(const float4*)(sj + j);
        uint32_t mw = (u & 2) ? ((u & 1) ? pk3 : pk2) : ((u & 1) ? pk1 : pk0);
        int sh = shg + ((u >> 2) << 2);
        float e0 = si + sv.x; e0 = fmaxf(e0, 0.2f * e0);
        float e1 = si + sv.y; e1 = fmaxf(e1, 0.2f * e1);
        float e2 = si + sv.z; e2 = fmaxf(e2, 0.2f * e2);
        float e3 = si + sv.w; e3 = fmaxf(e3, 0.2f * e3);
        float a0 = ((mw >> (sh + 0)) & 1u) ? __expf(e0) * il : 0.f;
        float a1 = ((mw >> (sh + 1)) & 1u) ? __expf(e1) * il : 0.f;
        float a2 = ((mw >> (sh + 2)) & 1u) ? __expf(e2) * il : 0.f;
        float a3 = ((mw >> (sh + 3)) & 1u) ? __expf(e3) * il : 0.f;
        f32x4 av = {a0, a1, a2, a3};
        __builtin_nontemporal_store(av, (f32x4*)(arow + j));
        union { __bf16 h[4]; uint2 u2; } pkv;
        pkv.h[0] = (__bf16)a0; pkv.h[1] = (__bf16)a1;
        pkv.h[2] = (__bf16)a2; pkv.h[3] = (__bf16)a3;
        *(uint2*)(&Pl[buf][ii * 72 + (sub << 2)]) = pkv.u2;
      }
      // counted barrier: gl_lds pair (issued last iter) retired at vmcnt(1);
      // newest alpha store floats across. lgkmcnt(0): Pl ds_write landed.
      asm volatile("s_waitcnt vmcnt(1) lgkmcnt(0)\n\ts_barrier" ::: "memory");
      // prefetch next tile into hl[buf^1]
      if (u < 7 || g < 3) {
        int jn = j0r + 64;
#pragma unroll
        for (int inst = 0; inst < 2; ++inst) {
          int row = (w << 4) + (inst << 3) + lrow;
          gl_lds16(hTb + (size_t)row * Nn + jn + ((ccs ^ lrow) << 3),
                   &hl[buf ^ 1][((w << 4) + (inst << 3)) << 6]);
        }
      }
      // pin the gl_lds pair before anything later (keeps vmcnt order exact)
      __builtin_amdgcn_sched_barrier(0);
      // MFMA: out[i0+iw..+16, nd0..+32] += P(16xK) @ hT-slices
#pragma unroll
      for (int ks = 0; ks < 2; ++ks) {
        bf16x8 af = *(const bf16x8*)(&Pl[buf][(iw + m16) * 72 + (ks << 5) + (q16 << 3)]);
        {
          int d = nd0 + m16;
          int phys = ((ks << 2) + q16) ^ (d & 7);
          bf16x8 bv = *(const bf16x8*)(&hl[buf][(d << 6) + (phys << 3)]);
          acc0 = __builtin_amdgcn_mfma_f32_16x16x32_bf16(af, bv, acc0, 0, 0, 0);
        }
        {
          int d = nd0 + 16 + m16;
          int phys = ((ks << 2) + q16) ^ (d & 7);
          bf16x8 bv = *(const bf16x8*)(&hl[buf][(d << 6) + (phys << 3)]);
          acc1 = __builtin_amdgcn_mfma_f32_16x16x32_bf16(af, bv, acc1, 0, 0, 0);
        }
      }
    }
  }

  // epilogue: D[row=(lane>>4)*4+r][col=lane&15]; row->i, col->d
#pragma unroll
  for (int nb = 0; nb < 2; ++nb) {
    f32x4 a = nb ? acc1 : acc0;
    int d = nd0 + (nb << 4) + m16;
#pragma unroll
    for (int r = 0; r < 4; ++r) {
      int irow = i0 + iw + (q16 << 2) + r;
      out[((size_t)(b * Nn + irow) << 7) + d] = a[r];
    }
  }
}

extern "C" void kernel_launch(void* const* d_in, const int* in_sizes, int n_in,
                              void* d_out, int out_size, void* d_ws, size_t ws_size,
                              hipStream_t stream) {
  const float* x = (const float*)d_in[0];
  const int* adj = (const int*)d_in[1];
  const float* W = (const float*)d_in[2];
  const float* a_vec = (const float*)d_in[3];

  float* out = (float*)d_out;
  float* alpha = out + (size_t)Bn * Nn * Dn;  // outputs concatenated: (out, alpha)

  char* ws = (char*)d_ws;
  __bf16* hT = (__bf16*)ws;                               // B*D*N bf16 = 4 MiB
  float* s1 = (float*)(ws + (size_t)Bn * Dn * Nn * 2);    // B*N fp32
  float* s2 = s1 + (size_t)Bn * Nn;                       // B*N fp32
  uint32_t* pkm = (uint32_t*)(s2 + (size_t)Bn * Nn);      // N*64 u32 = 512 KB

  gat_k1<<<512, 256, 0, stream>>>(x, W, a_vec, hT, s1, s2);
  gat_kpack<<<512, 256, 0, stream>>>(adj, pkm);
  gat_k2<<<512, 512, 0, stream>>>(pkm, hT, s1, s2, out, alpha);
}